// Round 1
// baseline (78.393 us; speedup 1.0000x reference)
//
#include <hip/hip_runtime.h>

#define DIM 4096
#define NE 8

// ---------------------------------------------------------------------------
// Kernel 1: ternary weight quantization (BitNet weight_quant).
//   ws = 1 / max(mean|W|, 1e-5)
//   t[e][i] = clip(rint(W[e][i]*ws), -1, 1)  stored TRANSPOSED as int8 [DIM][NE]
// Single block; W is only 128 KB.
// ---------------------------------------------------------------------------
__global__ __launch_bounds__(256) void wq_kernel(const float* __restrict__ W,
                                                 signed char* __restrict__ wq,
                                                 float* __restrict__ wscale) {
    __shared__ float red[4];
    const int tid  = threadIdx.x;
    const int lane = tid & 63;
    const int wid  = tid >> 6;

    const float4* W4 = (const float4*)W;   // 8192 float4s total
    float s = 0.f;
    #pragma unroll
    for (int r = 0; r < 32; ++r) {
        float4 w = W4[r * 256 + tid];
        s += fabsf(w.x) + fabsf(w.y) + fabsf(w.z) + fabsf(w.w);
    }
    #pragma unroll
    for (int o = 32; o > 0; o >>= 1) s += __shfl_xor(s, o, 64);
    if (lane == 0) red[wid] = s;
    __syncthreads();
    const float mean = (red[0] + red[1] + red[2] + red[3]) * (1.0f / (NE * DIM));
    const float ws   = 1.0f / fmaxf(mean, 1e-5f);
    if (tid == 0) *wscale = ws;

    // quantize + transpose scatter (tiny: 32 KB of byte stores)
    #pragma unroll
    for (int r = 0; r < 32; ++r) {
        const int f4 = r * 256 + tid;
        float4 w = W4[f4];
        const int f = f4 * 4;
        float vals[4] = {w.x, w.y, w.z, w.w};
        #pragma unroll
        for (int k = 0; k < 4; ++k) {
            float t = fminf(fmaxf(rintf(vals[k] * ws), -1.f), 1.f);
            const int e = (f + k) >> 12;          // expert (input layout [NE][DIM])
            const int i = (f + k) & (DIM - 1);    // dim index
            wq[i * NE + e] = (signed char)t;
        }
    }
}

// ---------------------------------------------------------------------------
// Kernel 2: per-token fused rmsnorm + act-quant + 8 ternary dots + softmax.
// One block per token; row (16 KB) lives in registers, read from HBM once.
// ---------------------------------------------------------------------------
__device__ __forceinline__ void mac8(float q, unsigned u0, unsigned u1, float* acc) {
    #pragma unroll
    for (int k = 0; k < 4; ++k) {
        acc[k]     = fmaf(q, (float)(signed char)(u0 >> (8 * k)), acc[k]);
        acc[k + 4] = fmaf(q, (float)(signed char)(u1 >> (8 * k)), acc[k + 4]);
    }
}

__global__ __launch_bounds__(256) void gate_kernel(const float* __restrict__ x,
                                                   const signed char* __restrict__ wq,
                                                   const float* __restrict__ wscale,
                                                   const float* __restrict__ bias,
                                                   float* __restrict__ out) {
    __shared__ float sred[4], ared[4];
    __shared__ float accred[4][NE];

    const int tid  = threadIdx.x;
    const int lane = tid & 63;
    const int wid  = tid >> 6;
    const size_t token = blockIdx.x;

    const float4* xrow = (const float4*)(x + token * DIM);

    // ---- pass 1: load row into registers, local sumsq + absmax ----
    float4 v[4];
    float ss = 0.f, amax = 0.f;
    #pragma unroll
    for (int r = 0; r < 4; ++r) {
        v[r] = xrow[r * 256 + tid];
        ss = fmaf(v[r].x, v[r].x, ss);
        ss = fmaf(v[r].y, v[r].y, ss);
        ss = fmaf(v[r].z, v[r].z, ss);
        ss = fmaf(v[r].w, v[r].w, ss);
        amax = fmaxf(amax, fmaxf(fmaxf(fabsf(v[r].x), fabsf(v[r].y)),
                                 fmaxf(fabsf(v[r].z), fabsf(v[r].w))));
    }
    #pragma unroll
    for (int o = 32; o > 0; o >>= 1) {
        ss  += __shfl_xor(ss, o, 64);
        amax = fmaxf(amax, __shfl_xor(amax, o, 64));
    }
    if (lane == 0) { sred[wid] = ss; ared[wid] = amax; }
    __syncthreads();
    ss   = sred[0] + sred[1] + sred[2] + sred[3];
    amax = fmaxf(fmaxf(ared[0], ared[1]), fmaxf(ared[2], ared[3]));

    // rmsnorm scale + activation-quant scale (per reference order of ops)
    const float n     = fmaxf(sqrtf(ss), 1e-12f);
    const float xnmax = (amax / n) * 64.0f;                 // max|xn|
    const float scale = 127.0f / fmaxf(xnmax, 1e-5f);       // act quant scale
    const float m     = (64.0f / n) * scale;                // combined x -> q multiplier

    // ---- pass 2 (registers): quantize + 8 ternary dot products ----
    float acc[NE] = {0, 0, 0, 0, 0, 0, 0, 0};
    #pragma unroll
    for (int r = 0; r < 4; ++r) {
        const int e4 = r * 256 + tid;                       // float4 index in row
        const uint4* wp = (const uint4*)(wq + (size_t)e4 * 32);
        const uint4 w0 = wp[0];   // elems 4e4, 4e4+1 (8 bytes each: experts 0-7)
        const uint4 w1 = wp[1];   // elems 4e4+2, 4e4+3
        const float q0 = fminf(fmaxf(rintf(v[r].x * m), -128.f), 127.f);
        const float q1 = fminf(fmaxf(rintf(v[r].y * m), -128.f), 127.f);
        const float q2 = fminf(fmaxf(rintf(v[r].z * m), -128.f), 127.f);
        const float q3 = fminf(fmaxf(rintf(v[r].w * m), -128.f), 127.f);
        mac8(q0, w0.x, w0.y, acc);
        mac8(q1, w0.z, w0.w, acc);
        mac8(q2, w1.x, w1.y, acc);
        mac8(q3, w1.z, w1.w, acc);
    }

    // ---- block reduce the 8 accumulators ----
    #pragma unroll
    for (int e = 0; e < NE; ++e) {
        #pragma unroll
        for (int o = 32; o > 0; o >>= 1) acc[e] += __shfl_xor(acc[e], o, 64);
    }
    if (lane == 0) {
        #pragma unroll
        for (int e = 0; e < NE; ++e) accred[wid][e] = acc[e];
    }
    __syncthreads();

    // ---- epilogue: logits, bias, softmax (thread 0) ----
    if (tid == 0) {
        const float inv = 1.0f / (scale * (*wscale));       // dot_int -> real units
        float logits[NE];
        float mx = -1e30f;
        #pragma unroll
        for (int e = 0; e < NE; ++e) {
            const float d = accred[0][e] + accred[1][e] + accred[2][e] + accred[3][e];
            logits[e] = d * inv + bias[e];
            mx = fmaxf(mx, logits[e]);
        }
        float sum = 0.f;
        #pragma unroll
        for (int e = 0; e < NE; ++e) { logits[e] = expf(logits[e] - mx); sum += logits[e]; }
        const float isum = 1.0f / sum;
        #pragma unroll
        for (int e = 0; e < NE; ++e) out[token * NE + e] = logits[e] * isum;
    }
}

// ---------------------------------------------------------------------------
extern "C" void kernel_launch(void* const* d_in, const int* in_sizes, int n_in,
                              void* d_out, int out_size, void* d_ws, size_t ws_size,
                              hipStream_t stream) {
    const float* x = (const float*)d_in[0];   // [4,4096,4096] fp32
    const float* W = (const float*)d_in[1];   // [8,4096] fp32
    const float* b = (const float*)d_in[2];   // [8] fp32
    float* out = (float*)d_out;               // [4,4096,8] fp32

    signed char* wq  = (signed char*)d_ws;                 // [DIM][NE] int8 (32 KB)
    float* wscale    = (float*)((char*)d_ws + DIM * NE);   // 1 float

    const int tokens = in_sizes[0] / DIM;     // 16384

    wq_kernel<<<1, 256, 0, stream>>>(W, wq, wscale);
    gate_kernel<<<tokens, 256, 0, stream>>>(x, wq, wscale, b, out);
}

// Round 2
// 51.695 us; speedup vs baseline: 1.5165x; 1.5165x over previous
//
#include <hip/hip_runtime.h>

#define DIM 4096
#define NE 8

// ---------------------------------------------------------------------------
// int8 4-way dot:  c += sum_k a.byte[k] * b.byte[k]   (signed)
// ---------------------------------------------------------------------------
#if __has_builtin(__builtin_amdgcn_sdot4)
__device__ __forceinline__ int dot4(int a, int b, int c) {
    return __builtin_amdgcn_sdot4(a, b, c, false);
}
#else
__device__ __forceinline__ int dot4(int a, int b, int c) {
    #pragma unroll
    for (int k = 0; k < 4; ++k)
        c += (int)(signed char)(a >> (8 * k)) * (int)(signed char)(b >> (8 * k));
    return c;
}
#endif

// pack low bytes of 4 ints into one dword: [q3|q2|q1|q0]
__device__ __forceinline__ unsigned pack4(int q0, int q1, int q2, int q3) {
    unsigned t0 = __builtin_amdgcn_perm((unsigned)q1, (unsigned)q0, 0x00000400u);
    unsigned t1 = __builtin_amdgcn_perm((unsigned)q3, (unsigned)q2, 0x00000400u);
    return __builtin_amdgcn_perm(t1, t0, 0x05040100u);
}

// ---------------------------------------------------------------------------
// Kernel 1a: partial abs-sums of W (32 blocks x 256 threads x float4)
// ---------------------------------------------------------------------------
__global__ __launch_bounds__(256) void wq_mean_kernel(const float* __restrict__ W,
                                                      float* __restrict__ partials) {
    __shared__ float red[4];
    const int tid = threadIdx.x, lane = tid & 63, wid = tid >> 6;
    float4 w = ((const float4*)W)[blockIdx.x * 256 + tid];
    float s = fabsf(w.x) + fabsf(w.y) + fabsf(w.z) + fabsf(w.w);
    #pragma unroll
    for (int o = 32; o > 0; o >>= 1) s += __shfl_xor(s, o, 64);
    if (lane == 0) red[wid] = s;
    __syncthreads();
    if (tid == 0) partials[blockIdx.x] = red[0] + red[1] + red[2] + red[3];
}

// ---------------------------------------------------------------------------
// Kernel 1b: ternary-quantize W, pack 4 consecutive elems/expert into a dword.
// Output layout: wq32[e * 1024 + g]  (g = 4-element group index within expert)
// ---------------------------------------------------------------------------
__global__ __launch_bounds__(256) void wq_quant_kernel(const float* __restrict__ W,
                                                       const float* __restrict__ partials,
                                                       unsigned* __restrict__ wq32,
                                                       float* __restrict__ wscale) {
    __shared__ float sws;
    const int tid = threadIdx.x;
    if (tid < 32) {
        float p = partials[tid];
        #pragma unroll
        for (int o = 16; o > 0; o >>= 1) p += __shfl_xor(p, o, 64);
        if (tid == 0) {
            const float mean = p * (1.0f / (NE * DIM));
            const float ws = 1.0f / fmaxf(mean, 1e-5f);
            sws = ws;
            if (blockIdx.x == 0) *wscale = ws;
        }
    }
    __syncthreads();
    const float ws = sws;
    const int idx = blockIdx.x * 256 + tid;          // dword index == e*1024+g
    float4 w = ((const float4*)W)[idx];
    const int q0 = min(max((int)rintf(w.x * ws), -1), 1);
    const int q1 = min(max((int)rintf(w.y * ws), -1), 1);
    const int q2 = min(max((int)rintf(w.z * ws), -1), 1);
    const int q3 = min(max((int)rintf(w.w * ws), -1), 1);
    wq32[idx] = pack4(q0, q1, q2, q3);
}

// ---------------------------------------------------------------------------
// Kernel 2: per-token fused rmsnorm + int8 act-quant + 8 ternary dots (sdot4)
// + softmax. One block per token; row lives in registers, read from HBM once.
// ---------------------------------------------------------------------------
__global__ __launch_bounds__(256) void gate_kernel(const float* __restrict__ x,
                                                   const unsigned* __restrict__ wq32,
                                                   const float* __restrict__ wscale,
                                                   const float* __restrict__ bias,
                                                   float* __restrict__ out) {
    __shared__ float sred[4], ared[4];
    __shared__ int accred[4][NE];

    const int tid = threadIdx.x, lane = tid & 63, wid = tid >> 6;
    const size_t token = blockIdx.x;
    const float4* xrow = (const float4*)(x + token * (size_t)DIM);

    // ---- weight dwords for this thread's 16 elements (L2-hot, issue early) ----
    unsigned wreg[4][NE];
    #pragma unroll
    for (int r = 0; r < 4; ++r) {
        const int e4 = r * 256 + tid;                // 4-elem group index 0..1023
        #pragma unroll
        for (int e = 0; e < NE; ++e) wreg[r][e] = wq32[e * 1024 + e4];
    }

    // ---- pass 1: load row into registers, sumsq + absmax ----
    float4 v[4];
    float ss = 0.f, amax = 0.f;
    #pragma unroll
    for (int r = 0; r < 4; ++r) {
        v[r] = xrow[r * 256 + tid];
        ss = fmaf(v[r].x, v[r].x, ss);
        ss = fmaf(v[r].y, v[r].y, ss);
        ss = fmaf(v[r].z, v[r].z, ss);
        ss = fmaf(v[r].w, v[r].w, ss);
        amax = fmaxf(amax, fmaxf(fmaxf(fabsf(v[r].x), fabsf(v[r].y)),
                                 fmaxf(fabsf(v[r].z), fabsf(v[r].w))));
    }
    #pragma unroll
    for (int o = 32; o > 0; o >>= 1) {
        ss  += __shfl_xor(ss, o, 64);
        amax = fmaxf(amax, __shfl_xor(amax, o, 64));
    }
    if (lane == 0) { sred[wid] = ss; ared[wid] = amax; }
    __syncthreads();
    ss   = sred[0] + sred[1] + sred[2] + sred[3];
    amax = fmaxf(fmaxf(ared[0], ared[1]), fmaxf(ared[2], ared[3]));

    const float n     = fmaxf(sqrtf(ss), 1e-12f);
    const float xnmax = (amax / n) * 64.0f;               // max|xn|
    const float scale = 127.0f / fmaxf(xnmax, 1e-5f);     // act-quant scale
    const float m     = (64.0f / n) * scale;              // x -> q multiplier

    // ---- pass 2: quantize in-register + sdot4 against 8 experts ----
    int acc[NE] = {0, 0, 0, 0, 0, 0, 0, 0};
    #pragma unroll
    for (int r = 0; r < 4; ++r) {
        const int q0 = (int)rintf(v[r].x * m);            // |q|<=127 by construction
        const int q1 = (int)rintf(v[r].y * m);
        const int q2 = (int)rintf(v[r].z * m);
        const int q3 = (int)rintf(v[r].w * m);
        const int packed = (int)pack4(q0, q1, q2, q3);
        #pragma unroll
        for (int e = 0; e < NE; ++e) acc[e] = dot4(packed, (int)wreg[r][e], acc[e]);
    }

    // ---- value-splitting butterfly: lane ends with full-wave sum of expert lane&7 ----
    #pragma unroll
    for (int j = 0; j < 4; ++j) {
        const int give = (lane & 1) ? acc[2*j] : acc[2*j+1];
        const int got  = __shfl_xor(give, 1, 64);
        const int keep = (lane & 1) ? acc[2*j+1] : acc[2*j];
        acc[j] = keep + got;
    }
    #pragma unroll
    for (int j = 0; j < 2; ++j) {
        const int give = (lane & 2) ? acc[2*j] : acc[2*j+1];
        const int got  = __shfl_xor(give, 2, 64);
        const int keep = (lane & 2) ? acc[2*j+1] : acc[2*j];
        acc[j] = keep + got;
    }
    {
        const int give = (lane & 4) ? acc[0] : acc[1];
        const int got  = __shfl_xor(give, 4, 64);
        const int keep = (lane & 4) ? acc[1] : acc[0];
        acc[0] = keep + got;
    }
    #pragma unroll
    for (int o = 8; o < 64; o <<= 1) acc[0] += __shfl_xor(acc[0], o, 64);

    if (lane < NE) accred[wid][lane] = acc[0];
    __syncthreads();

    // ---- epilogue: lanes 0..7 do bias + softmax, one coalesced 32B store ----
    if (tid < NE) {
        const float inv = 1.0f / (scale * (*wscale));
        const int tot = accred[0][tid] + accred[1][tid] + accred[2][tid] + accred[3][tid];
        float logit = (float)tot * inv + bias[tid];
        float mx = logit;
        #pragma unroll
        for (int o = 1; o < NE; o <<= 1) mx = fmaxf(mx, __shfl_xor(mx, o, 64));
        const float p = expf(logit - mx);
        float s = p;
        #pragma unroll
        for (int o = 1; o < NE; o <<= 1) s += __shfl_xor(s, o, 64);
        out[token * NE + tid] = p / s;
    }
}

// ---------------------------------------------------------------------------
extern "C" void kernel_launch(void* const* d_in, const int* in_sizes, int n_in,
                              void* d_out, int out_size, void* d_ws, size_t ws_size,
                              hipStream_t stream) {
    const float* x = (const float*)d_in[0];   // [4,4096,4096] fp32
    const float* W = (const float*)d_in[1];   // [8,4096] fp32
    const float* b = (const float*)d_in[2];   // [8] fp32
    float* out = (float*)d_out;               // [4,4096,8] fp32

    unsigned* wq32   = (unsigned*)d_ws;                          // 32 KB packed ternary
    float* wscale    = (float*)((char*)d_ws + 32768);            // 1 float
    float* partials  = (float*)((char*)d_ws + 32768 + 64);       // 32 floats

    const int tokens = in_sizes[0] / DIM;     // 16384

    wq_mean_kernel <<<32, 256, 0, stream>>>(W, partials);
    wq_quant_kernel<<<32, 256, 0, stream>>>(W, partials, wq32, wscale);
    gate_kernel<<<tokens, 256, 0, stream>>>(x, wq32, wscale, b, out);
}